// Round 4
// baseline (3247.053 us; speedup 1.0000x reference)
//
#include <hip/hip_runtime.h>
#include <hip/hip_bf16.h>
#include <cmath>

// ============================================================================
// RAE forward, round 4: convs on MFMA via bf16x3 split precision.
//   fp32 value v == hi + lo (two RNE bf16 legs), product via 3 MFMAs
//   (AhBh + AhBl + AlBh), fp32 accumulate. Activations/weights stored as
//   packed ushort2{hi,lo} (one uint) planes, split ONCE at production.
//   dists/softmix/prototype path stays pure fp32.
// Deconv = 4 parity sub-convs (disjoint outputs, gridDim.z = parity),
// identical im2col geometry to the audited fp32 version.
// Round-4 delta: template<DEC,BM> — BM=128 (wave tile 64x64, acc[4][4]) for
// big layers (conv2, dconv2, dconv3); BM=64 for small ones (occupancy).
// ============================================================================

typedef short bf16x8 __attribute__((ext_vector_type(8)));
typedef float f32x4  __attribute__((ext_vector_type(4)));

__device__ __forceinline__ ushort f2bf(float f) {
    uint u = __float_as_uint(f);
    return (ushort)((u + 0x7fffu + ((u >> 16) & 1u)) >> 16);   // RNE
}
__device__ __forceinline__ float bf2f(ushort h) {
    return __uint_as_float(((uint)h) << 16);                   // exact
}
__device__ __forceinline__ uint pack2(float v) {
    ushort h = f2bf(v);
    ushort l = f2bf(v - bf2f(h));
    return (uint)h | ((uint)l << 16);
}
__device__ __forceinline__ float unpack2(uint u) {
    return bf2f((ushort)(u & 0xffffu)) + bf2f((ushort)(u >> 16));
}

// ---------------------------------------------------------------------------
// repack + split: wtp[(t*C+c)*O+o] = pack2(W[o][c][t])
// ---------------------------------------------------------------------------
__global__ __launch_bounds__(256)
void repack_kernel(const float* __restrict__ W, uint* __restrict__ wtp, int O, int C)
{
    int i = blockIdx.x * 256 + threadIdx.x;
    int total = O * C * 9;
    if (i >= total) return;
    int o = i % O;
    int rest = i / O;
    int c = rest % C;
    int t = rest / C;
    wtp[i] = pack2(W[(o * C + c) * 9 + t]);
}

// ---------------------------------------------------------------------------
// conv1: x(256,3,64,64) fp32 -> y(256,128,32,32) packed, stride2 pad1 k3, relu.
// grid (B, 8 o-groups), block 256.
// ---------------------------------------------------------------------------
__global__ __launch_bounds__(256)
void conv1_kernel(const float* __restrict__ x, const float* __restrict__ W,
                  const float* __restrict__ bias, uint* __restrict__ y)
{
    __shared__ float xs[3 * 64 * 64];
    __shared__ float ws[16 * 27];
    __shared__ float bs[16];
    const int n = blockIdx.x, og = blockIdx.y;
    const int tid = threadIdx.x;
    const float* xp = x + (size_t)n * 3 * 64 * 64;
    for (int i = tid; i < 3 * 64 * 64 / 4; i += 256)
        ((float4*)xs)[i] = ((const float4*)xp)[i];
    for (int i = tid; i < 16 * 27; i += 256)
        ws[i] = W[(og * 16 + i / 27) * 27 + i % 27];
    if (tid < 16) bs[tid] = bias[og * 16 + tid];
    __syncthreads();

    for (int p = 0; p < 4; p++) {
        int pos = tid + 256 * p;
        int u = pos >> 5, v = pos & 31;
        float xv[27];
#pragma unroll
        for (int c = 0; c < 3; c++)
#pragma unroll
            for (int kh = 0; kh < 3; kh++)
#pragma unroll
                for (int kw = 0; kw < 3; kw++) {
                    int iu = 2 * u - 1 + kh, iv = 2 * v - 1 + kw;
                    bool ok = (iu >= 0) & (iu < 64) & (iv >= 0) & (iv < 64);
                    xv[c * 9 + kh * 3 + kw] = ok ? xs[(c << 12) + (iu << 6) + iv] : 0.f;
                }
        for (int oi = 0; oi < 16; oi++) {
            float acc = bs[oi];
#pragma unroll
            for (int t = 0; t < 27; t++) acc = fmaf(xv[t], ws[oi * 27 + t], acc);
            y[((size_t)(n * 128 + og * 16 + oi) * 32 + u) * 32 + v] = pack2(fmaxf(acc, 0.f));
        }
    }
}

// ---------------------------------------------------------------------------
// MFMA implicit-GEMM conv (bf16x3). BM in {64,128} (o), BN=128 (s), BK=32.
// 4 waves 2x2; wave tile (BM/2)x64 = MFR x 4 frags of 16x16x32.
// ENC: y[n,o,u,v] = sum x[n,c,2u-1+kh,2v-1+kw]*W[o,c,kh,kw]
// DEC parity (pi,pj): y[n,o,2u+pi,2v+pj] = sum_{taps} x[n,c,u-da,v-db]*W
//   pi==0 -> (da,kh) in {(0,2),(1,0)}; pi==1 -> {(0,1)} (same horizontally).
// x, wt, y are packed uint{hi,lo}. fout: optional fp32 sideband (latent).
// A frag: lane holds A[m=lane&15][k=8*(lane>>4)+j]; B symmetric; C/D:
// col=lane&15, row=4*(lane>>4)+i  (learn_hip m89-verified convention).
// ---------------------------------------------------------------------------
template<bool DEC, int BM>
__global__ __launch_bounds__(256)
void conv_mfma(const uint* __restrict__ x, const uint* __restrict__ wt,
               const float* __restrict__ bias, uint* __restrict__ y,
               float* __restrict__ fout,
               int C, int Hi, int Wi, int O, int Ho, int Wo,
               int lgGW, int lgGHW, int act)
{
    constexpr int MFR = BM / 32;                   // m-frags per wave (2 or 4)
    constexpr int ACH = BM / 64;                   // A k-chunks per thread
    __shared__ __align__(16) ushort Ash[BM][40];   // [m][k], 80B rows (pad 8)
    __shared__ __align__(16) ushort Asl[BM][40];
    __shared__ __align__(16) ushort Bsh[128][40];  // [n][k]
    __shared__ __align__(16) ushort Bsl[128][40];

    const int tid = threadIdx.x;
    const int lane = tid & 63, wv = tid >> 6;
    const int wr = wv >> 1, wc = wv & 1;
    const int lr = lane & 15, lq = lane >> 4;

    const int o0 = blockIdx.y * BM;
    const int s0 = blockIdx.x * 128;

    int pi = 0, pj = 0, ntv = 0, nth = 0;
    if (DEC) {
        pi = blockIdx.z >> 1; pj = blockIdx.z & 1;
        ntv = (pi == 1) ? 1 : 2;
        nth = (pj == 1) ? 1 : 2;
    }
    const int HiWi = Hi * Wi;
    const int gwm = (1 << lgGW) - 1, ghwm = (1 << lgGHW) - 1;

    // B staging coords: thread owns one n, two k-chunks (kcB, kcB+2)
    const int nB_loc = (tid & 63) + 64 * (wv & 1);
    const int kcB = wv >> 1;                 // 0..1
    const int sB = s0 + nB_loc;
    const int nImg = sB >> lgGHW;
    const int rB = sB & ghwm;
    const int uB = rB >> lgGW, vB = rB & gwm;
    const int xnbase = nImg * C * HiWi;

    // A staging coords: thread owns one m, ACH k-chunks
    const int mA = tid & (BM - 1);
    const int kcA0 = (tid / BM) * ACH;

    f32x4 acc[MFR][4] = {};

    const int ntaps = DEC ? ntv * nth : 9;
    for (int t = 0; t < ntaps; t++) {
        int tapidx, gbase; bool valid;
        if (!DEC) {
            int kh = t / 3, kw = t % 3;
            tapidx = t;
            int iu = 2 * uB - 1 + kh, iv = 2 * vB - 1 + kw;
            valid = (iu >= 0) & (iu < Hi) & (iv >= 0) & (iv < Wi);
            gbase = xnbase + iu * Wi + iv;
        } else {
            int itv = t / nth, ith = t - (t / nth) * nth;
            int kh = (pi == 1) ? 1 : 2 - 2 * itv;   // da = itv
            int kw = (pj == 1) ? 1 : 2 - 2 * ith;   // db = ith
            tapidx = kh * 3 + kw;
            int a = uB - itv, b2 = vB - ith;
            valid = (a >= 0) & (b2 >= 0);
            gbase = xnbase + a * Wi + b2;
        }
        const uint* wtap = wt + (size_t)tapidx * C * O;
        for (int c0 = 0; c0 < C; c0 += 32) {
            __syncthreads();   // WAR: previous step's frag reads done
            {   // stage A: Ash/Asl[m][k] = wt[tap][c0+k][o0+m]
#pragma unroll
                for (int q = 0; q < ACH; q++) {
                    const int kc = kcA0 + q;
                    const uint* wp = wtap + (size_t)(c0 + 8 * kc) * O + o0 + mA;
                    uint u0[8];
#pragma unroll
                    for (int j = 0; j < 8; j++) u0[j] = wp[j * O];
                    bf16x8 vh, vl;
#pragma unroll
                    for (int j = 0; j < 8; j++) {
                        vh[j] = (short)(u0[j] & 0xffffu);
                        vl[j] = (short)(u0[j] >> 16);
                    }
                    *(bf16x8*)&Ash[mA][8 * kc] = vh;
                    *(bf16x8*)&Asl[mA][8 * kc] = vl;
                }
            }
            {   // stage B: Bsh/Bsl[n][k] = x[im2col gather]
#pragma unroll
                for (int q2 = 0; q2 < 2; q2++) {
                    const int kc = kcB + 2 * q2;
                    uint u0[8];
#pragma unroll
                    for (int j = 0; j < 8; j++)
                        u0[j] = valid ? x[gbase + (c0 + 8 * kc + j) * HiWi] : 0u;
                    bf16x8 vh, vl;
#pragma unroll
                    for (int j = 0; j < 8; j++) {
                        vh[j] = (short)(u0[j] & 0xffffu);
                        vl[j] = (short)(u0[j] >> 16);
                    }
                    *(bf16x8*)&Bsh[nB_loc][8 * kc] = vh;
                    *(bf16x8*)&Bsl[nB_loc][8 * kc] = vl;
                }
            }
            __syncthreads();
            bf16x8 bh[4], bl[4];
#pragma unroll
            for (int nf = 0; nf < 4; nf++) {
                const int n = wc * 64 + nf * 16 + lr;
                bh[nf] = *(const bf16x8*)&Bsh[n][8 * lq];
                bl[nf] = *(const bf16x8*)&Bsl[n][8 * lq];
            }
#pragma unroll
            for (int mf = 0; mf < MFR; mf++) {
                const int m = wr * (BM / 2) + mf * 16 + lr;
                bf16x8 ah = *(const bf16x8*)&Ash[m][8 * lq];
                bf16x8 al = *(const bf16x8*)&Asl[m][8 * lq];
#pragma unroll
                for (int nf = 0; nf < 4; nf++) {
                    acc[mf][nf] = __builtin_amdgcn_mfma_f32_16x16x32_bf16(ah, bh[nf], acc[mf][nf], 0, 0, 0);
                    acc[mf][nf] = __builtin_amdgcn_mfma_f32_16x16x32_bf16(ah, bl[nf], acc[mf][nf], 0, 0, 0);
                    acc[mf][nf] = __builtin_amdgcn_mfma_f32_16x16x32_bf16(al, bh[nf], acc[mf][nf], 0, 0, 0);
                }
            }
        }
    }

    const int HoWo = Ho * Wo;
#pragma unroll
    for (int mf = 0; mf < MFR; mf++) {
#pragma unroll
        for (int i = 0; i < 4; i++) {
            const int o = o0 + wr * (BM / 2) + mf * 16 + 4 * lq + i;
            const float bv = bias[o];
#pragma unroll
            for (int nf = 0; nf < 4; nf++) {
                const int s = s0 + wc * 64 + nf * 16 + lr;
                const int n = s >> lgGHW;
                const int r = s & ghwm;
                const int u = r >> lgGW, v = r & gwm;
                const int U = DEC ? 2 * u + pi : u;
                const int V = DEC ? 2 * v + pj : v;
                float val = acc[mf][nf][i] + bv;
                val = (act == 0) ? fmaxf(val, 0.f) : 1.f / (1.f + expf(-val));
                const size_t oi = (size_t)n * O * HoWo + (size_t)o * HoWo + U * Wo + V;
                y[oi] = pack2(val);
                if (fout) fout[oi] = val;
            }
        }
    }
}

// ---------------------------------------------------------------------------
// dconv4: x(B,128,32,32) packed -> y(B,3,64,64) fp32, sigmoid. O=3 direct.
// grid (4, B, 4 parity), block 256.
// ---------------------------------------------------------------------------
__global__ __launch_bounds__(256)
void dconv4_kernel(const uint* __restrict__ x, const float* __restrict__ W,
                   const float* __restrict__ bias, float* __restrict__ y)
{
    __shared__ float ws[3 * 128 * 9];
    const int tid = threadIdx.x;
    for (int i = tid; i < 3456; i += 256) ws[i] = W[i];
    __syncthreads();
    const int n = blockIdx.y;
    const int pi = blockIdx.z >> 1, pj = blockIdx.z & 1;
    const int idx = blockIdx.x * 256 + tid;
    const int u = idx >> 5, v = idx & 31;
    const int ntv = (pi == 1) ? 1 : 2;
    const int nth = (pj == 1) ? 1 : 2;
    float acc0 = bias[0], acc1 = bias[1], acc2 = bias[2];
    const uint* xp = x + (size_t)n * 128 * 1024;
    for (int c = 0; c < 128; c++) {
        const uint* xc = xp + c * 1024;
        for (int itv = 0; itv < ntv; itv++) {
            int a = u - itv; if (a < 0) continue;
            int kh = (pi == 1) ? 1 : 2 - 2 * itv;
            for (int ith = 0; ith < nth; ith++) {
                int b2 = v - ith; if (b2 < 0) continue;
                int kw = (pj == 1) ? 1 : 2 - 2 * ith;
                float xv = unpack2(xc[(a << 5) + b2]);
                int tt = c * 9 + kh * 3 + kw;
                acc0 = fmaf(xv, ws[tt], acc0);
                acc1 = fmaf(xv, ws[1152 + tt], acc1);
                acc2 = fmaf(xv, ws[2304 + tt], acc2);
            }
        }
    }
    const int uo = 2 * u + pi, vo = 2 * v + pj;
    const size_t base = (size_t)n * 3 * 4096 + (uo << 6) + vo;
    y[base]          = 1.f / (1.f + expf(-acc0));
    y[base + 4096]   = 1.f / (1.f + expf(-acc1));
    y[base + 8192]   = 1.f / (1.f + expf(-acc2));
}

// ---------------------------------------------------------------------------
// pnorm[gp] = ||proto_gp||^2.  grid 256, block 64.
// ---------------------------------------------------------------------------
__global__ __launch_bounds__(64)
void pnorm_kernel(const float* __restrict__ protos, float* __restrict__ pnorm)
{
    const int gp = blockIdx.x, lane = threadIdx.x;
    const float* pr = protos + (size_t)gp * 4096;
    float s = 0.f;
    for (int d = lane; d < 4096; d += 64) s = fmaf(pr[d], pr[d], s);
#pragma unroll
    for (int off = 32; off; off >>= 1) s += __shfl_xor(s, off);
    if (lane == 0) pnorm[gp] = s;
}

// ---------------------------------------------------------------------------
// dists[b,g,p] = ||z||^2 + ||p||^2 - 2 z.p (expanded, matches reference).
// 4 batch rows per block. grid 64, block 256. latent fp32.
// ---------------------------------------------------------------------------
__global__ __launch_bounds__(256)
void dists_kernel(const float* __restrict__ latent, const float* __restrict__ protos,
                  const float* __restrict__ pnorm, float* __restrict__ dists)
{
    __shared__ float zl[4][4096];
    __shared__ float znl[4];
    const int b0 = blockIdx.x * 4, tid = threadIdx.x;
    const float* zp = latent + (size_t)b0 * 4096;
    for (int i = tid; i < 4096; i += 256)
        ((float4*)&zl[0][0])[i] = ((const float4*)zp)[i];
    __syncthreads();
    const int w = tid >> 6, lane = tid & 63;
    {
        float s = 0.f;
        for (int d = lane; d < 4096; d += 64) s = fmaf(zl[w][d], zl[w][d], s);
#pragma unroll
        for (int off = 32; off; off >>= 1) s += __shfl_xor(s, off);
        if (lane == 0) znl[w] = s;
    }
    __syncthreads();
    for (int i = 0; i < 64; i++) {
        const int gp = w * 64 + i;
        const float* pr = protos + (size_t)gp * 4096;
        float dot[4] = {0.f, 0.f, 0.f, 0.f};
        for (int d = lane; d < 4096; d += 64) {
            float pv = pr[d];
#pragma unroll
            for (int bb = 0; bb < 4; bb++) dot[bb] = fmaf(zl[bb][d], pv, dot[bb]);
        }
#pragma unroll
        for (int bb = 0; bb < 4; bb++)
#pragma unroll
            for (int off = 32; off; off >>= 1) dot[bb] += __shfl_xor(dot[bb], off);
        if (lane == 0) {
            const float pn = pnorm[gp];
#pragma unroll
            for (int bb = 0; bb < 4; bb++)
                dists[(size_t)(b0 + bb) * 256 + gp] = znl[bb] + pn - 2.f * dot[bb];
        }
    }
}

// ---------------------------------------------------------------------------
// softmin per (b,g), then mixed[b,d] = 0.25*sum_g pw[g,d]*sum_p sm*proto.
// Writes fp32 mixed (d_out) AND packed bufM. 4 rows/block, grid 64.
// ---------------------------------------------------------------------------
__global__ __launch_bounds__(256)
void softmix_kernel(const float* __restrict__ dists, const float* __restrict__ protos,
                    const float* __restrict__ pw, float* __restrict__ mixed,
                    uint* __restrict__ mixedp)
{
    __shared__ float sml[4][256];
    const int b0 = blockIdx.x * 4, tid = threadIdx.x;
    const int w = tid >> 6, lane = tid & 63;
#pragma unroll
    for (int g = 0; g < 4; g++) {
        float d = -dists[(size_t)(b0 + w) * 256 + g * 64 + lane];
        float m = d;
#pragma unroll
        for (int off = 32; off; off >>= 1) m = fmaxf(m, __shfl_xor(m, off));
        float e = expf(d - m);
        float s = e;
#pragma unroll
        for (int off = 32; off; off >>= 1) s += __shfl_xor(s, off);
        sml[w][g * 64 + lane] = e / s;
    }
    __syncthreads();
    for (int d = tid; d < 4096; d += 256) {
        float accg[4][4];
#pragma unroll
        for (int bb = 0; bb < 4; bb++)
#pragma unroll
            for (int g = 0; g < 4; g++) accg[bb][g] = 0.f;
#pragma unroll
        for (int g = 0; g < 4; g++)
            for (int p = 0; p < 64; p++) {
                float pv = protos[(size_t)(g * 64 + p) * 4096 + d];
#pragma unroll
                for (int bb = 0; bb < 4; bb++)
                    accg[bb][g] = fmaf(sml[bb][g * 64 + p], pv, accg[bb][g]);
            }
        float pwv[4];
#pragma unroll
        for (int g = 0; g < 4; g++) pwv[g] = pw[g * 4096 + d];
#pragma unroll
        for (int bb = 0; bb < 4; bb++) {
            float m = 0.f;
#pragma unroll
            for (int g = 0; g < 4; g++) m = fmaf(pwv[g], accg[bb][g], m);
            m *= 0.25f;
            mixed[(size_t)(b0 + bb) * 4096 + d] = m;
            mixedp[(size_t)(b0 + bb) * 4096 + d] = pack2(m);
        }
    }
}

// ============================================================================
extern "C" void kernel_launch(void* const* d_in, const int* in_sizes, int n_in,
                              void* d_out, int out_size, void* d_ws, size_t ws_size,
                              hipStream_t stream)
{
    const float* x    = (const float*)d_in[0];
    const float* We1  = (const float*)d_in[1];  const float* be1 = (const float*)d_in[2];
    const float* We2  = (const float*)d_in[3];  const float* be2 = (const float*)d_in[4];
    const float* We3  = (const float*)d_in[5];  const float* be3 = (const float*)d_in[6];
    const float* We4  = (const float*)d_in[7];  const float* be4 = (const float*)d_in[8];
    const float* Wd1  = (const float*)d_in[9];  const float* bd1 = (const float*)d_in[10];
    const float* Wd2  = (const float*)d_in[11]; const float* bd2 = (const float*)d_in[12];
    const float* Wd3  = (const float*)d_in[13]; const float* bd3 = (const float*)d_in[14];
    const float* Wd4  = (const float*)d_in[15]; const float* bd4 = (const float*)d_in[16];
    const float* protos = (const float*)d_in[17];
    const float* pw   = (const float*)d_in[18];

    float* out = (float*)d_out;
    float* recon_img   = out;               // (256,3,64,64)
    float* recon_proto = out + 3145728;     // (256,3,64,64)
    float* dists       = out + 6291456;     // (256,4,64)
    float* latent      = out + 6356992;     // (256,256,4,4) fp32
    float* out_protos  = out + 7405568;     // (4,64,4096)
    float* mixed       = out + 8454144;     // (256,4096)

    uint* wsu  = (uint*)d_ws;               // ~185 MB used (4B elems)
    uint* bufA = wsu;                       // 33,554,432  packed (y1 / h3)
    uint* bufB = bufA + 33554432;           //  8,388,608  packed (y2 / h2)
    uint* bufC = bufB + 8388608;            //  2,097,152  packed (y3 / h1)
    uint* bufL = bufC + 2097152;            //  1,048,576  packed latent
    uint* bufM = bufL + 1048576;            //  1,048,576  packed mixed
    uint* wt_c2 = bufM + 1048576;           //    147,456
    uint* wt_c3 = wt_c2 + 147456;
    uint* wt_c4 = wt_c3 + 147456;           //    294,912
    uint* wt_d1 = wt_c4 + 294912;           //    294,912
    uint* wt_d2 = wt_d1 + 294912;
    uint* wt_d3 = wt_d2 + 147456;
    float* pnorm = (float*)(wt_d3 + 147456);//        256

    // weight repack+split (d_ws re-poisoned every call -> redo every call)
    repack_kernel<<<576, 256, 0, stream>>>(We2, wt_c2, 128, 128);
    repack_kernel<<<576, 256, 0, stream>>>(We3, wt_c3, 128, 128);
    repack_kernel<<<1152, 256, 0, stream>>>(We4, wt_c4, 256, 128);
    repack_kernel<<<1152, 256, 0, stream>>>(Wd1, wt_d1, 128, 256);
    repack_kernel<<<576, 256, 0, stream>>>(Wd2, wt_d2, 128, 128);
    repack_kernel<<<576, 256, 0, stream>>>(Wd3, wt_d3, 128, 128);
    pnorm_kernel<<<256, 64, 0, stream>>>(protos, pnorm);

    // encoder
    conv1_kernel<<<dim3(256, 8), 256, 0, stream>>>(x, We1, be1, bufA);
    conv_mfma<false, 128><<<dim3(512, 1), 256, 0, stream>>>(
        bufA, wt_c2, be2, bufB, nullptr, 128, 32, 32, 128, 16, 16, 4, 8, 0);
    conv_mfma<false, 64><<<dim3(128, 2), 256, 0, stream>>>(
        bufB, wt_c3, be3, bufC, nullptr, 128, 16, 16, 128, 8, 8, 3, 6, 0);
    conv_mfma<false, 64><<<dim3(32, 4), 256, 0, stream>>>(
        bufC, wt_c4, be4, bufL, latent, 128, 8, 8, 256, 4, 4, 2, 4, 1);

    // prototype block (fp32)
    dists_kernel<<<64, 256, 0, stream>>>(latent, protos, pnorm, dists);
    softmix_kernel<<<64, 256, 0, stream>>>(dists, protos, pw, mixed, bufM);
    hipMemcpyAsync(out_protos, protos, 1048576 * sizeof(float),
                   hipMemcpyDeviceToDevice, stream);

    // two decoders (share scratch; stream order serializes)
    for (int pass = 0; pass < 2; pass++) {
        const uint* src = (pass == 0) ? bufM : bufL;   // (B,256,4,4) packed
        float* dst = (pass == 0) ? recon_proto : recon_img;
        conv_mfma<true, 64><<<dim3(32, 2, 4), 256, 0, stream>>>(
            src, wt_d1, bd1, bufC, nullptr, 256, 4, 4, 128, 8, 8, 2, 4, 0);
        conv_mfma<true, 128><<<dim3(128, 1, 4), 256, 0, stream>>>(
            bufC, wt_d2, bd2, bufB, nullptr, 128, 8, 8, 128, 16, 16, 3, 6, 0);
        conv_mfma<true, 128><<<dim3(512, 1, 4), 256, 0, stream>>>(
            bufB, wt_d3, bd3, bufA, nullptr, 128, 16, 16, 128, 32, 32, 4, 8, 0);
        dconv4_kernel<<<dim3(4, 256, 4), 256, 0, stream>>>(bufA, Wd4, bd4, dst);
    }
}

// Round 5
// 1530.094 us; speedup vs baseline: 2.1221x; 2.1221x over previous
//
#include <hip/hip_runtime.h>
#include <hip/hip_bf16.h>
#include <cmath>

// ============================================================================
// RAE forward, round 5: convs on MFMA via bf16x3 split precision (unchanged
// from round 4, validated absmax=0.0078). Round-5 delta: prototype block
// de-latency-bound — dists as split-K partial dots (512 blocks) + finalize;
// softmix d-chunked (1024 blocks). Accumulation order per output element
// preserved exactly -> numerics identical to the passing round-4 version.
// ============================================================================

typedef short bf16x8 __attribute__((ext_vector_type(8)));
typedef float f32x4  __attribute__((ext_vector_type(4)));

__device__ __forceinline__ ushort f2bf(float f) {
    uint u = __float_as_uint(f);
    return (ushort)((u + 0x7fffu + ((u >> 16) & 1u)) >> 16);   // RNE
}
__device__ __forceinline__ float bf2f(ushort h) {
    return __uint_as_float(((uint)h) << 16);                   // exact
}
__device__ __forceinline__ uint pack2(float v) {
    ushort h = f2bf(v);
    ushort l = f2bf(v - bf2f(h));
    return (uint)h | ((uint)l << 16);
}
__device__ __forceinline__ float unpack2(uint u) {
    return bf2f((ushort)(u & 0xffffu)) + bf2f((ushort)(u >> 16));
}

// ---------------------------------------------------------------------------
// repack + split: wtp[(t*C+c)*O+o] = pack2(W[o][c][t])
// ---------------------------------------------------------------------------
__global__ __launch_bounds__(256)
void repack_kernel(const float* __restrict__ W, uint* __restrict__ wtp, int O, int C)
{
    int i = blockIdx.x * 256 + threadIdx.x;
    int total = O * C * 9;
    if (i >= total) return;
    int o = i % O;
    int rest = i / O;
    int c = rest % C;
    int t = rest / C;
    wtp[i] = pack2(W[(o * C + c) * 9 + t]);
}

// ---------------------------------------------------------------------------
// conv1: x(256,3,64,64) fp32 -> y(256,128,32,32) packed, stride2 pad1 k3, relu.
// ---------------------------------------------------------------------------
__global__ __launch_bounds__(256)
void conv1_kernel(const float* __restrict__ x, const float* __restrict__ W,
                  const float* __restrict__ bias, uint* __restrict__ y)
{
    __shared__ float xs[3 * 64 * 64];
    __shared__ float ws[16 * 27];
    __shared__ float bs[16];
    const int n = blockIdx.x, og = blockIdx.y;
    const int tid = threadIdx.x;
    const float* xp = x + (size_t)n * 3 * 64 * 64;
    for (int i = tid; i < 3 * 64 * 64 / 4; i += 256)
        ((float4*)xs)[i] = ((const float4*)xp)[i];
    for (int i = tid; i < 16 * 27; i += 256)
        ws[i] = W[(og * 16 + i / 27) * 27 + i % 27];
    if (tid < 16) bs[tid] = bias[og * 16 + tid];
    __syncthreads();

    for (int p = 0; p < 4; p++) {
        int pos = tid + 256 * p;
        int u = pos >> 5, v = pos & 31;
        float xv[27];
#pragma unroll
        for (int c = 0; c < 3; c++)
#pragma unroll
            for (int kh = 0; kh < 3; kh++)
#pragma unroll
                for (int kw = 0; kw < 3; kw++) {
                    int iu = 2 * u - 1 + kh, iv = 2 * v - 1 + kw;
                    bool ok = (iu >= 0) & (iu < 64) & (iv >= 0) & (iv < 64);
                    xv[c * 9 + kh * 3 + kw] = ok ? xs[(c << 12) + (iu << 6) + iv] : 0.f;
                }
        for (int oi = 0; oi < 16; oi++) {
            float acc = bs[oi];
#pragma unroll
            for (int t = 0; t < 27; t++) acc = fmaf(xv[t], ws[oi * 27 + t], acc);
            y[((size_t)(n * 128 + og * 16 + oi) * 32 + u) * 32 + v] = pack2(fmaxf(acc, 0.f));
        }
    }
}

// ---------------------------------------------------------------------------
// MFMA implicit-GEMM conv (bf16x3). BM in {64,128}, BN=128, BK=32.
// (unchanged from validated round-4 version)
// ---------------------------------------------------------------------------
template<bool DEC, int BM>
__global__ __launch_bounds__(256)
void conv_mfma(const uint* __restrict__ x, const uint* __restrict__ wt,
               const float* __restrict__ bias, uint* __restrict__ y,
               float* __restrict__ fout,
               int C, int Hi, int Wi, int O, int Ho, int Wo,
               int lgGW, int lgGHW, int act)
{
    constexpr int MFR = BM / 32;
    constexpr int ACH = BM / 64;
    __shared__ __align__(16) ushort Ash[BM][40];
    __shared__ __align__(16) ushort Asl[BM][40];
    __shared__ __align__(16) ushort Bsh[128][40];
    __shared__ __align__(16) ushort Bsl[128][40];

    const int tid = threadIdx.x;
    const int lane = tid & 63, wv = tid >> 6;
    const int wr = wv >> 1, wc = wv & 1;
    const int lr = lane & 15, lq = lane >> 4;

    const int o0 = blockIdx.y * BM;
    const int s0 = blockIdx.x * 128;

    int pi = 0, pj = 0, ntv = 0, nth = 0;
    if (DEC) {
        pi = blockIdx.z >> 1; pj = blockIdx.z & 1;
        ntv = (pi == 1) ? 1 : 2;
        nth = (pj == 1) ? 1 : 2;
    }
    const int HiWi = Hi * Wi;
    const int gwm = (1 << lgGW) - 1, ghwm = (1 << lgGHW) - 1;

    const int nB_loc = (tid & 63) + 64 * (wv & 1);
    const int kcB = wv >> 1;
    const int sB = s0 + nB_loc;
    const int nImg = sB >> lgGHW;
    const int rB = sB & ghwm;
    const int uB = rB >> lgGW, vB = rB & gwm;
    const int xnbase = nImg * C * HiWi;

    const int mA = tid & (BM - 1);
    const int kcA0 = (tid / BM) * ACH;

    f32x4 acc[MFR][4] = {};

    const int ntaps = DEC ? ntv * nth : 9;
    for (int t = 0; t < ntaps; t++) {
        int tapidx, gbase; bool valid;
        if (!DEC) {
            int kh = t / 3, kw = t % 3;
            tapidx = t;
            int iu = 2 * uB - 1 + kh, iv = 2 * vB - 1 + kw;
            valid = (iu >= 0) & (iu < Hi) & (iv >= 0) & (iv < Wi);
            gbase = xnbase + iu * Wi + iv;
        } else {
            int itv = t / nth, ith = t - (t / nth) * nth;
            int kh = (pi == 1) ? 1 : 2 - 2 * itv;
            int kw = (pj == 1) ? 1 : 2 - 2 * ith;
            tapidx = kh * 3 + kw;
            int a = uB - itv, b2 = vB - ith;
            valid = (a >= 0) & (b2 >= 0);
            gbase = xnbase + a * Wi + b2;
        }
        const uint* wtap = wt + (size_t)tapidx * C * O;
        for (int c0 = 0; c0 < C; c0 += 32) {
            __syncthreads();
            {
#pragma unroll
                for (int q = 0; q < ACH; q++) {
                    const int kc = kcA0 + q;
                    const uint* wp = wtap + (size_t)(c0 + 8 * kc) * O + o0 + mA;
                    uint u0[8];
#pragma unroll
                    for (int j = 0; j < 8; j++) u0[j] = wp[j * O];
                    bf16x8 vh, vl;
#pragma unroll
                    for (int j = 0; j < 8; j++) {
                        vh[j] = (short)(u0[j] & 0xffffu);
                        vl[j] = (short)(u0[j] >> 16);
                    }
                    *(bf16x8*)&Ash[mA][8 * kc] = vh;
                    *(bf16x8*)&Asl[mA][8 * kc] = vl;
                }
            }
            {
#pragma unroll
                for (int q2 = 0; q2 < 2; q2++) {
                    const int kc = kcB + 2 * q2;
                    uint u0[8];
#pragma unroll
                    for (int j = 0; j < 8; j++)
                        u0[j] = valid ? x[gbase + (c0 + 8 * kc + j) * HiWi] : 0u;
                    bf16x8 vh, vl;
#pragma unroll
                    for (int j = 0; j < 8; j++) {
                        vh[j] = (short)(u0[j] & 0xffffu);
                        vl[j] = (short)(u0[j] >> 16);
                    }
                    *(bf16x8*)&Bsh[nB_loc][8 * kc] = vh;
                    *(bf16x8*)&Bsl[nB_loc][8 * kc] = vl;
                }
            }
            __syncthreads();
            bf16x8 bh[4], bl[4];
#pragma unroll
            for (int nf = 0; nf < 4; nf++) {
                const int n = wc * 64 + nf * 16 + lr;
                bh[nf] = *(const bf16x8*)&Bsh[n][8 * lq];
                bl[nf] = *(const bf16x8*)&Bsl[n][8 * lq];
            }
#pragma unroll
            for (int mf = 0; mf < MFR; mf++) {
                const int m = wr * (BM / 2) + mf * 16 + lr;
                bf16x8 ah = *(const bf16x8*)&Ash[m][8 * lq];
                bf16x8 al = *(const bf16x8*)&Asl[m][8 * lq];
#pragma unroll
                for (int nf = 0; nf < 4; nf++) {
                    acc[mf][nf] = __builtin_amdgcn_mfma_f32_16x16x32_bf16(ah, bh[nf], acc[mf][nf], 0, 0, 0);
                    acc[mf][nf] = __builtin_amdgcn_mfma_f32_16x16x32_bf16(ah, bl[nf], acc[mf][nf], 0, 0, 0);
                    acc[mf][nf] = __builtin_amdgcn_mfma_f32_16x16x32_bf16(al, bh[nf], acc[mf][nf], 0, 0, 0);
                }
            }
        }
    }

    const int HoWo = Ho * Wo;
#pragma unroll
    for (int mf = 0; mf < MFR; mf++) {
#pragma unroll
        for (int i = 0; i < 4; i++) {
            const int o = o0 + wr * (BM / 2) + mf * 16 + 4 * lq + i;
            const float bv = bias[o];
#pragma unroll
            for (int nf = 0; nf < 4; nf++) {
                const int s = s0 + wc * 64 + nf * 16 + lr;
                const int n = s >> lgGHW;
                const int r = s & ghwm;
                const int u = r >> lgGW, v = r & gwm;
                const int U = DEC ? 2 * u + pi : u;
                const int V = DEC ? 2 * v + pj : v;
                float val = acc[mf][nf][i] + bv;
                val = (act == 0) ? fmaxf(val, 0.f) : 1.f / (1.f + expf(-val));
                const size_t oi = (size_t)n * O * HoWo + (size_t)o * HoWo + U * Wo + V;
                y[oi] = pack2(val);
                if (fout) fout[oi] = val;
            }
        }
    }
}

// ---------------------------------------------------------------------------
// dconv4: x(B,128,32,32) packed -> y(B,3,64,64) fp32, sigmoid. O=3 direct.
// ---------------------------------------------------------------------------
__global__ __launch_bounds__(256)
void dconv4_kernel(const uint* __restrict__ x, const float* __restrict__ W,
                   const float* __restrict__ bias, float* __restrict__ y)
{
    __shared__ float ws[3 * 128 * 9];
    const int tid = threadIdx.x;
    for (int i = tid; i < 3456; i += 256) ws[i] = W[i];
    __syncthreads();
    const int n = blockIdx.y;
    const int pi = blockIdx.z >> 1, pj = blockIdx.z & 1;
    const int idx = blockIdx.x * 256 + tid;
    const int u = idx >> 5, v = idx & 31;
    const int ntv = (pi == 1) ? 1 : 2;
    const int nth = (pj == 1) ? 1 : 2;
    float acc0 = bias[0], acc1 = bias[1], acc2 = bias[2];
    const uint* xp = x + (size_t)n * 128 * 1024;
    for (int c = 0; c < 128; c++) {
        const uint* xc = xp + c * 1024;
        for (int itv = 0; itv < ntv; itv++) {
            int a = u - itv; if (a < 0) continue;
            int kh = (pi == 1) ? 1 : 2 - 2 * itv;
            for (int ith = 0; ith < nth; ith++) {
                int b2 = v - ith; if (b2 < 0) continue;
                int kw = (pj == 1) ? 1 : 2 - 2 * ith;
                float xv = unpack2(xc[(a << 5) + b2]);
                int tt = c * 9 + kh * 3 + kw;
                acc0 = fmaf(xv, ws[tt], acc0);
                acc1 = fmaf(xv, ws[1152 + tt], acc1);
                acc2 = fmaf(xv, ws[2304 + tt], acc2);
            }
        }
    }
    const int uo = 2 * u + pi, vo = 2 * v + pj;
    const size_t base = (size_t)n * 3 * 4096 + (uo << 6) + vo;
    y[base]          = 1.f / (1.f + expf(-acc0));
    y[base + 4096]   = 1.f / (1.f + expf(-acc1));
    y[base + 8192]   = 1.f / (1.f + expf(-acc2));
}

// ---------------------------------------------------------------------------
// rownorm[r] = ||row_r||^2 over 4096 cols. Used for protos (256 rows) AND
// latent-as-z (256 rows). grid 256, block 64.
// ---------------------------------------------------------------------------
__global__ __launch_bounds__(64)
void pnorm_kernel(const float* __restrict__ rows, float* __restrict__ norms)
{
    const int r = blockIdx.x, lane = threadIdx.x;
    const float* pr = rows + (size_t)r * 4096;
    float s = 0.f;
    for (int d = lane; d < 4096; d += 64) s = fmaf(pr[d], pr[d], s);
#pragma unroll
    for (int off = 32; off; off >>= 1) s += __shfl_xor(s, off);
    if (lane == 0) norms[r] = s;
}

// ---------------------------------------------------------------------------
// Split-K partial dots: dotpart[ks][b][gp] = sum_{d in chunk ks} z[b,d]*p[gp,d]
// grid (64 bgroups, 8 kchunks), block 256 (4 waves; wave w owns gp rows
// w*64..w*64+63). 512 blocks -> 8 waves/CU, latency hidden.
// ---------------------------------------------------------------------------
__global__ __launch_bounds__(256)
void dists_part_kernel(const float* __restrict__ latent, const float* __restrict__ protos,
                       float* __restrict__ dotpart)
{
    __shared__ float zl[4][512];    // 8 KB
    const int b0 = blockIdx.x * 4, ks = blockIdx.y, tid = threadIdx.x;
    for (int i = tid; i < 512; i += 256) {          // 512 float4s = 4 rows x 512 f
        int bb = i >> 7, off = i & 127;
        ((float4*)&zl[bb][0])[off] =
            ((const float4*)(latent + (size_t)(b0 + bb) * 4096 + ks * 512))[off];
    }
    __syncthreads();
    const int w = tid >> 6, lane = tid & 63;
    for (int i = 0; i < 64; i++) {
        const int gp = w * 64 + i;
        const float* pr = protos + (size_t)gp * 4096 + ks * 512;
        float dot[4] = {0.f, 0.f, 0.f, 0.f};
#pragma unroll
        for (int d8 = 0; d8 < 8; d8++) {
            const int d = lane + 64 * d8;
            const float pv = pr[d];
#pragma unroll
            for (int bb = 0; bb < 4; bb++) dot[bb] = fmaf(zl[bb][d], pv, dot[bb]);
        }
#pragma unroll
        for (int bb = 0; bb < 4; bb++)
#pragma unroll
            for (int off = 32; off; off >>= 1) dot[bb] += __shfl_xor(dot[bb], off);
        if (lane == 0) {
#pragma unroll
            for (int bb = 0; bb < 4; bb++)
                dotpart[(size_t)ks * 65536 + (size_t)(b0 + bb) * 256 + gp] = dot[bb];
        }
    }
}

// ---------------------------------------------------------------------------
// dists[b*256+gp] = znorm[b] + pnorm[gp] - 2*sum_ks dotpart. grid 256.
// ---------------------------------------------------------------------------
__global__ __launch_bounds__(256)
void dists_final_kernel(const float* __restrict__ dotpart, const float* __restrict__ znorm,
                        const float* __restrict__ pnorm, float* __restrict__ dists)
{
    const int i = blockIdx.x * 256 + threadIdx.x;   // 65536
    const int b = i >> 8, gp = i & 255;
    float s = 0.f;
#pragma unroll
    for (int ks = 0; ks < 8; ks++) s += dotpart[(size_t)ks * 65536 + i];
    dists[i] = znorm[b] + pnorm[gp] - 2.f * s;
}

// ---------------------------------------------------------------------------
// softmin per (b,g), then mixed[b,d] = 0.25*sum_g pw[g,d]*sum_p sm*proto.
// grid (64 bgroups, 16 dchunks); each thread owns exactly one d.
// Per-(b,d) accumulation order identical to the validated round-4 version.
// ---------------------------------------------------------------------------
__global__ __launch_bounds__(256)
void softmix_kernel(const float* __restrict__ dists, const float* __restrict__ protos,
                    const float* __restrict__ pw, float* __restrict__ mixed,
                    uint* __restrict__ mixedp)
{
    __shared__ float sml[4][256];
    const int b0 = blockIdx.x * 4, d0 = blockIdx.y * 256, tid = threadIdx.x;
    const int w = tid >> 6, lane = tid & 63;
#pragma unroll
    for (int g = 0; g < 4; g++) {       // wave w owns batch row b0+w
        float dv = -dists[(size_t)(b0 + w) * 256 + g * 64 + lane];
        float m = dv;
#pragma unroll
        for (int off = 32; off; off >>= 1) m = fmaxf(m, __shfl_xor(m, off));
        float e = expf(dv - m);
        float s = e;
#pragma unroll
        for (int off = 32; off; off >>= 1) s += __shfl_xor(s, off);
        sml[w][g * 64 + lane] = e / s;
    }
    __syncthreads();
    const int d = d0 + tid;
    float accg[4][4];
#pragma unroll
    for (int bb = 0; bb < 4; bb++)
#pragma unroll
        for (int g = 0; g < 4; g++) accg[bb][g] = 0.f;
#pragma unroll
    for (int g = 0; g < 4; g++)
        for (int p = 0; p < 64; p++) {
            float pv = protos[(size_t)(g * 64 + p) * 4096 + d];
#pragma unroll
            for (int bb = 0; bb < 4; bb++)
                accg[bb][g] = fmaf(sml[bb][g * 64 + p], pv, accg[bb][g]);
        }
    float pwv[4];
#pragma unroll
    for (int g = 0; g < 4; g++) pwv[g] = pw[g * 4096 + d];
#pragma unroll
    for (int bb = 0; bb < 4; bb++) {
        float m = 0.f;
#pragma unroll
        for (int g = 0; g < 4; g++) m = fmaf(pwv[g], accg[bb][g], m);
        m *= 0.25f;
        mixed[(size_t)(b0 + bb) * 4096 + d] = m;
        mixedp[(size_t)(b0 + bb) * 4096 + d] = pack2(m);
    }
}

// ============================================================================
extern "C" void kernel_launch(void* const* d_in, const int* in_sizes, int n_in,
                              void* d_out, int out_size, void* d_ws, size_t ws_size,
                              hipStream_t stream)
{
    const float* x    = (const float*)d_in[0];
    const float* We1  = (const float*)d_in[1];  const float* be1 = (const float*)d_in[2];
    const float* We2  = (const float*)d_in[3];  const float* be2 = (const float*)d_in[4];
    const float* We3  = (const float*)d_in[5];  const float* be3 = (const float*)d_in[6];
    const float* We4  = (const float*)d_in[7];  const float* be4 = (const float*)d_in[8];
    const float* Wd1  = (const float*)d_in[9];  const float* bd1 = (const float*)d_in[10];
    const float* Wd2  = (const float*)d_in[11]; const float* bd2 = (const float*)d_in[12];
    const float* Wd3  = (const float*)d_in[13]; const float* bd3 = (const float*)d_in[14];
    const float* Wd4  = (const float*)d_in[15]; const float* bd4 = (const float*)d_in[16];
    const float* protos = (const float*)d_in[17];
    const float* pw   = (const float*)d_in[18];

    float* out = (float*)d_out;
    float* recon_img   = out;               // (256,3,64,64)
    float* recon_proto = out + 3145728;     // (256,3,64,64)
    float* dists       = out + 6291456;     // (256,4,64)
    float* latent      = out + 6356992;     // (256,256,4,4) fp32
    float* out_protos  = out + 7405568;     // (4,64,4096)
    float* mixed       = out + 8454144;     // (256,4096)

    uint* wsu  = (uint*)d_ws;
    uint* bufA = wsu;                       // 33,554,432  packed (y1 / h3)
    uint* bufB = bufA + 33554432;           //  8,388,608  packed (y2 / h2)
    uint* bufC = bufB + 8388608;            //  2,097,152  packed (y3 / h1)
    uint* bufL = bufC + 2097152;            //  1,048,576  packed latent
    uint* bufM = bufL + 1048576;            //  1,048,576  packed mixed
    uint* wt_c2 = bufM + 1048576;           //    147,456
    uint* wt_c3 = wt_c2 + 147456;
    uint* wt_c4 = wt_c3 + 147456;           //    294,912
    uint* wt_d1 = wt_c4 + 294912;           //    294,912
    uint* wt_d2 = wt_d1 + 294912;
    uint* wt_d3 = wt_d2 + 147456;
    float* pnorm = (float*)(wt_d3 + 147456);    //     256
    float* znorm = pnorm + 256;                 //     256
    float* dotpart = znorm + 256;               // 524,288 (8 x 256 x 256)

    // weight repack+split (d_ws re-poisoned every call -> redo every call)
    repack_kernel<<<576, 256, 0, stream>>>(We2, wt_c2, 128, 128);
    repack_kernel<<<576, 256, 0, stream>>>(We3, wt_c3, 128, 128);
    repack_kernel<<<1152, 256, 0, stream>>>(We4, wt_c4, 256, 128);
    repack_kernel<<<1152, 256, 0, stream>>>(Wd1, wt_d1, 128, 256);
    repack_kernel<<<576, 256, 0, stream>>>(Wd2, wt_d2, 128, 128);
    repack_kernel<<<576, 256, 0, stream>>>(Wd3, wt_d3, 128, 128);
    pnorm_kernel<<<256, 64, 0, stream>>>(protos, pnorm);

    // encoder
    conv1_kernel<<<dim3(256, 8), 256, 0, stream>>>(x, We1, be1, bufA);
    conv_mfma<false, 128><<<dim3(512, 1), 256, 0, stream>>>(
        bufA, wt_c2, be2, bufB, nullptr, 128, 32, 32, 128, 16, 16, 4, 8, 0);
    conv_mfma<false, 64><<<dim3(128, 2), 256, 0, stream>>>(
        bufB, wt_c3, be3, bufC, nullptr, 128, 16, 16, 128, 8, 8, 3, 6, 0);
    conv_mfma<false, 64><<<dim3(32, 4), 256, 0, stream>>>(
        bufC, wt_c4, be4, bufL, latent, 128, 8, 8, 256, 4, 4, 2, 4, 1);

    // prototype block (fp32, parallelized)
    pnorm_kernel<<<256, 64, 0, stream>>>(latent, znorm);
    dists_part_kernel<<<dim3(64, 8), 256, 0, stream>>>(latent, protos, dotpart);
    dists_final_kernel<<<256, 256, 0, stream>>>(dotpart, znorm, pnorm, dists);
    softmix_kernel<<<dim3(64, 16), 256, 0, stream>>>(dists, protos, pw, mixed, bufM);
    hipMemcpyAsync(out_protos, protos, 1048576 * sizeof(float),
                   hipMemcpyDeviceToDevice, stream);

    // two decoders (share scratch; stream order serializes)
    for (int pass = 0; pass < 2; pass++) {
        const uint* src = (pass == 0) ? bufM : bufL;   // (B,256,4,4) packed
        float* dst = (pass == 0) ? recon_proto : recon_img;
        conv_mfma<true, 64><<<dim3(32, 2, 4), 256, 0, stream>>>(
            src, wt_d1, bd1, bufC, nullptr, 256, 4, 4, 128, 8, 8, 2, 4, 0);
        conv_mfma<true, 128><<<dim3(128, 1, 4), 256, 0, stream>>>(
            bufC, wt_d2, bd2, bufB, nullptr, 128, 8, 8, 128, 16, 16, 3, 6, 0);
        conv_mfma<true, 128><<<dim3(512, 1, 4), 256, 0, stream>>>(
            bufB, wt_d3, bd3, bufA, nullptr, 128, 16, 16, 128, 32, 32, 4, 8, 0);
        dconv4_kernel<<<dim3(4, 256, 4), 256, 0, stream>>>(bufA, Wd4, bd4, dst);
    }
}